// Round 3
// baseline (10526.012 us; speedup 1.0000x reference)
//
#include <hip/hip_runtime.h>
#include <math.h>

#define SQ3F   1.7320508075688772f
#define SQRT8F 2.8284271247461903f

__device__ __forceinline__ float fast_silu(float x) {
    return x * __builtin_amdgcn_rcpf(1.0f + __expf(-x));
}

// ---------------------------------------------------------------- transpose w2
__global__ __launch_bounds__(256) void tr_kernel(const float* __restrict__ w2,
                                                 float* __restrict__ w2t) {
    const int t = blockIdx.x * 256 + threadIdx.x;   // 8192 = 128 x 64
    if (t < 8192) {
        const int o = t >> 6, i = t & 63;
        w2t[t] = w2[i * 128 + o];                   // w2t[o][i] = w2[i][o]
    }
}

// ---------------------------------------------------------------- up-projection
// xall[n][m] = float4{ xs[n][m], xv[n][m][0], xv[n][m][1], xv[n][m][2] }
__global__ __launch_bounds__(256) void up_kernel(const float* __restrict__ nf,
                                                 const float* __restrict__ Wu0,
                                                 const float* __restrict__ Wu1,
                                                 float* __restrict__ xall, int N) {
    __shared__ float sW0[1024], sW1[1024];
    for (int i = threadIdx.x; i < 1024; i += 256) { sW0[i] = Wu0[i]; sW1[i] = Wu1[i]; }
    __syncthreads();
    const int t = blockIdx.x * 256 + threadIdx.x;
    const int n = t >> 5, k = t & 31;
    if (n >= N) return;
    const float* row = nf + (size_t)n * 128;
    float a0 = 0.f, a1 = 0.f, a2 = 0.f, a3 = 0.f;
#pragma unroll
    for (int m = 0; m < 32; ++m) {
        const float wa = sW0[m * 32 + k], wb = sW1[m * 32 + k];
        a0 += row[m] * wa;
        a1 += row[32 + m * 3 + 0] * wb;
        a2 += row[32 + m * 3 + 1] * wb;
        a3 += row[32 + m * 3 + 2] * wb;
    }
    const float s = 0.17677669529663687f;  // 1/sqrt(32)
    float4 o; o.x = a0 * s; o.y = a1 * s; o.z = a2 * s; o.w = a3 * s;
    reinterpret_cast<float4*>(xall)[(size_t)n * 32 + k] = o;
}

// ---------------------------------------------------------------- edge kernel
// lane = edge. Weights are wave-uniform -> SGPR operands.
// h0[64] in static VGPRs; h1 staged per-wave in LDS [i][lane] (conflict-free).
__global__ __launch_bounds__(128) void ek(const float* __restrict__ edge_vec,
                                          const float* __restrict__ edge_len,
                                          const int*  __restrict__ senders,
                                          const int*  __restrict__ receivers,
                                          const float* __restrict__ w0,   // (8,64)
                                          const float* __restrict__ b0,   // 64
                                          const float* __restrict__ w1,   // (64,64)
                                          const float* __restrict__ b1,   // 64
                                          const float* __restrict__ b2,   // 128
                                          const float* __restrict__ w2t,  // (128,64)
                                          const float4* __restrict__ xall,
                                          float* __restrict__ msg,        // N x 256
                                          int E) {
    __shared__ float h1t[2][64][64];                // 32 KiB / block (2 waves)
    const int lane = threadIdx.x & 63;
    float (*h1w)[64] = h1t[threadIdx.x >> 6];

    const int wave   = (blockIdx.x * blockDim.x + threadIdx.x) >> 6;
    const int nwaves = (gridDim.x * blockDim.x) >> 6;
    const int NP     = (E + 63) >> 6;

    for (int pass = wave; pass < NP; pass += nwaves) {
        int e = pass * 64 + lane;
        const bool valid = e < E;
        if (!valid) e = E - 1;

        const float ev0 = edge_vec[e * 3 + 0];
        const float ev1 = edge_vec[e * 3 + 1];
        const float ev2 = edge_vec[e * 3 + 2];
        const float r   = edge_len[e];
        const int snd = senders[e];
        const int rcv = receivers[e];

        // Y1 = sqrt(3) * ev / (|ev| + 1e-12)
        const float nrm = sqrtf(ev0 * ev0 + ev1 * ev1 + ev2 * ev2) + 1e-12f;
        const float sc  = SQ3F * __builtin_amdgcn_rcpf(nrm);
        const float Y0 = ev0 * sc, Y1 = ev1 * sc, Y2 = ev2 * sc;

        // radial embedding
        const float xcl  = fminf(fmaxf(r, 0.0f), 1.0f);
        const float gate = (r <= 1.0f) ? SQRT8F : 0.0f;
        float emb[8];
#pragma unroll
        for (int i = 0; i < 8; ++i) {
            const float d = xcl * 7.0f - (float)i;
            emb[i] = __expf(-0.5f * d * d) * gate;
        }

        // layer 1: 8 -> 64, h0 in static regs
        float h0[64];
#pragma unroll
        for (int o = 0; o < 64; ++o) {
            float a = b0[o];
#pragma unroll
            for (int i = 0; i < 8; ++i) a += emb[i] * w0[i * 64 + o];
            h0[o] = fast_silu(a);
        }

        // layer 2: 64 -> 64, h1 -> LDS column [i][lane]
#pragma unroll 1
        for (int ob = 0; ob < 64; ob += 8) {
            float a[8];
#pragma unroll
            for (int u = 0; u < 8; ++u) a[u] = b1[ob + u];
#pragma unroll
            for (int i = 0; i < 64; ++i) {
                const float hv = h0[i];
#pragma unroll
                for (int u = 0; u < 8; ++u) a[u] += hv * w1[i * 64 + ob + u];
            }
#pragma unroll
            for (int u = 0; u < 8; ++u) h1w[ob + u][lane] = fast_silu(a[u]);
        }

        // layer 3 + messages, two m-values per iteration
        const float4* xrow = xall + (size_t)snd * 32;
        float* mrow = msg + (size_t)rcv * 256;

#pragma unroll 1
        for (int m = 0; m < 32; m += 2) {
            const float* r0 = w2t + m * 64;          // path 0 rows m, m+1
            const float* r1 = w2t + (32 + m) * 64;   // path 1
            const float* r2 = w2t + (64 + m) * 64;   // path 2
            const float* r3 = w2t + (96 + m) * 64;   // path 3
            float d00 = b2[m],     d01 = b2[32 + m], d02 = b2[64 + m], d03 = b2[96 + m];
            float d10 = b2[m + 1], d11 = b2[33 + m], d12 = b2[65 + m], d13 = b2[97 + m];
#pragma unroll
            for (int i = 0; i < 64; ++i) {
                const float hv = h1w[i][lane];
                d00 += hv * r0[i];      d01 += hv * r1[i];
                d02 += hv * r2[i];      d03 += hv * r3[i];
                d10 += hv * r0[64 + i]; d11 += hv * r1[64 + i];
                d12 += hv * r2[64 + i]; d13 += hv * r3[64 + i];
            }
            const float4 g0 = xrow[m];
            const float4 g1 = xrow[m + 1];
            if (valid) {
                {
                    const float ss = g0.x;
                    const float t1 = d01 * ss;
                    const float dv = g0.y * Y0 + g0.z * Y1 + g0.w * Y2;
                    atomicAdd(mrow + m,                 d00 * ss);
                    atomicAdd(mrow + 32 + m,            d03 * dv * (1.0f / SQ3F));
                    atomicAdd(mrow + 64 + m * 3 + 0,    t1 * Y0);
                    atomicAdd(mrow + 64 + m * 3 + 1,    t1 * Y1);
                    atomicAdd(mrow + 64 + m * 3 + 2,    t1 * Y2);
                    atomicAdd(mrow + 160 + m * 3 + 0,   d02 * g0.y);
                    atomicAdd(mrow + 160 + m * 3 + 1,   d02 * g0.z);
                    atomicAdd(mrow + 160 + m * 3 + 2,   d02 * g0.w);
                }
                {
                    const int mq = m + 1;
                    const float ss = g1.x;
                    const float t1 = d11 * ss;
                    const float dv = g1.y * Y0 + g1.z * Y1 + g1.w * Y2;
                    atomicAdd(mrow + mq,                d10 * ss);
                    atomicAdd(mrow + 32 + mq,           d13 * dv * (1.0f / SQ3F));
                    atomicAdd(mrow + 64 + mq * 3 + 0,   t1 * Y0);
                    atomicAdd(mrow + 64 + mq * 3 + 1,   t1 * Y1);
                    atomicAdd(mrow + 64 + mq * 3 + 2,   t1 * Y2);
                    atomicAdd(mrow + 160 + mq * 3 + 0,  d12 * g1.y);
                    atomicAdd(mrow + 160 + mq * 3 + 1,  d12 * g1.z);
                    atomicAdd(mrow + 160 + mq * 3 + 2,  d12 * g1.w);
                }
            }
        }
    }
}

// ---------------------------------------------------------------- out-projection
__global__ __launch_bounds__(256) void out_kernel(const float* __restrict__ msg,
                                                  const float* __restrict__ Wo0,
                                                  const float* __restrict__ Wo1,
                                                  float* __restrict__ out, int N) {
    __shared__ float s0[2048], s1[2048];
    for (int i = threadIdx.x; i < 2048; i += 256) { s0[i] = Wo0[i]; s1[i] = Wo1[i]; }
    __syncthreads();
    const int t = blockIdx.x * 256 + threadIdx.x;
    const int n = t >> 7, j = t & 127;
    if (n >= N) return;
    const float* mrow = msg + (size_t)n * 256;
    float acc = 0.0f;
    if (j < 32) {
#pragma unroll
        for (int mm = 0; mm < 64; ++mm) acc += mrow[mm] * s0[mm * 32 + j];
    } else {
        const int jj = j - 32;
        const int k = jj / 3, c = jj - 3 * k;
        const float* mv = mrow + 64 + c;
#pragma unroll
        for (int mm = 0; mm < 64; ++mm) acc += mv[mm * 3] * s1[mm * 32 + k];
    }
    out[(size_t)n * 128 + j] = acc * (1.0f / 128.0f);  // (1/sqrt(64)) * (1/16)
}

extern "C" void kernel_launch(void* const* d_in, const int* in_sizes, int n_in,
                              void* d_out, int out_size, void* d_ws, size_t ws_size,
                              hipStream_t stream) {
    const float* node_feats = (const float*)d_in[0];
    const float* edge_vec   = (const float*)d_in[1];
    const float* edge_len   = (const float*)d_in[2];
    const int*   senders    = (const int*)d_in[3];
    const int*   receivers  = (const int*)d_in[4];
    // d_in[5]: num_nodes scalar (derived from sizes instead)
    const float* W_up0  = (const float*)d_in[6];
    const float* W_up1  = (const float*)d_in[7];
    const float* mlp_w0 = (const float*)d_in[8];
    const float* mlp_b0 = (const float*)d_in[9];
    const float* mlp_w1 = (const float*)d_in[10];
    const float* mlp_b1 = (const float*)d_in[11];
    const float* mlp_w2 = (const float*)d_in[12];
    const float* mlp_b2 = (const float*)d_in[13];
    const float* W_out0 = (const float*)d_in[14];
    const float* W_out1 = (const float*)d_in[15];

    const int N = in_sizes[0] / 128;
    const int E = in_sizes[1] / 3;

    float* xall = (float*)d_ws;                  // N*128 f32 (float4-interleaved)
    float* msg  = xall + (size_t)N * 128;        // N*256 f32 (atomic accumulators)
    float* w2t  = msg + (size_t)N * 256;         // 8192 f32 (transposed mlp_w2)

    tr_kernel<<<32, 256, 0, stream>>>(mlp_w2, w2t);
    up_kernel<<<(N * 32 + 255) / 256, 256, 0, stream>>>(node_feats, W_up0, W_up1, xall, N);
    hipMemsetAsync(msg, 0, (size_t)N * 256 * sizeof(float), stream);
    ek<<<1280, 128, 0, stream>>>(edge_vec, edge_len, senders, receivers,
                                 mlp_w0, mlp_b0, mlp_w1, mlp_b1, mlp_b2, w2t,
                                 (const float4*)xall, msg, E);
    out_kernel<<<(N * 128 + 255) / 256, 256, 0, stream>>>(msg, W_out0, W_out1,
                                                          (float*)d_out, N);
}

// Round 4
// 10501.581 us; speedup vs baseline: 1.0023x; 1.0023x over previous
//
#include <hip/hip_runtime.h>
#include <math.h>

#define SQ3F   1.7320508075688772f
#define SQRT8F 2.8284271247461903f

__device__ __forceinline__ float fast_silu(float x) {
    return x * __builtin_amdgcn_rcpf(1.0f + __expf(-x));
}

// ---------------------------------------------------------------- transpose w2
__global__ __launch_bounds__(256) void tr_kernel(const float* __restrict__ w2,
                                                 float* __restrict__ w2t) {
    const int t = blockIdx.x * 256 + threadIdx.x;   // 8192 = 128 x 64
    if (t < 8192) {
        const int o = t >> 6, i = t & 63;
        w2t[t] = w2[i * 128 + o];                   // w2t[o][i] = w2[i][o]
    }
}

// ---------------------------------------------------------------- up-projection
__global__ __launch_bounds__(256) void up_kernel(const float* __restrict__ nf,
                                                 const float* __restrict__ Wu0,
                                                 const float* __restrict__ Wu1,
                                                 float* __restrict__ xall, int N) {
    __shared__ float sW0[1024], sW1[1024];
    for (int i = threadIdx.x; i < 1024; i += 256) { sW0[i] = Wu0[i]; sW1[i] = Wu1[i]; }
    __syncthreads();
    const int t = blockIdx.x * 256 + threadIdx.x;
    const int n = t >> 5, k = t & 31;
    if (n >= N) return;
    const float* row = nf + (size_t)n * 128;
    float a0 = 0.f, a1 = 0.f, a2 = 0.f, a3 = 0.f;
#pragma unroll
    for (int m = 0; m < 32; ++m) {
        const float wa = sW0[m * 32 + k], wb = sW1[m * 32 + k];
        a0 += row[m] * wa;
        a1 += row[32 + m * 3 + 0] * wb;
        a2 += row[32 + m * 3 + 1] * wb;
        a3 += row[32 + m * 3 + 2] * wb;
    }
    const float s = 0.17677669529663687f;  // 1/sqrt(32)
    float4 o; o.x = a0 * s; o.y = a1 * s; o.z = a2 * s; o.w = a3 * s;
    reinterpret_cast<float4*>(xall)[(size_t)n * 32 + k] = o;
}

// ---------------------------------------------------------------- CSR build
__global__ __launch_bounds__(256) void hist_kernel(const int* __restrict__ rcv,
                                                   int* __restrict__ cnt, int E) {
    const int t = blockIdx.x * 256 + threadIdx.x;
    if (t < E) atomicAdd(&cnt[rcv[t]], 1);
}

__global__ __launch_bounds__(1024) void scan_kernel(const int* __restrict__ cnt,
                                                    int* __restrict__ off, int N, int E) {
    __shared__ int part[1024];
    const int t = threadIdx.x;
    const int CH = (N + 1023) / 1024;
    const int lo = t * CH;
    const int hi = (lo + CH < N) ? lo + CH : N;
    int s = 0;
    for (int i = lo; i < hi; ++i) s += cnt[i];
    part[t] = s;
    __syncthreads();
    for (int d = 1; d < 1024; d <<= 1) {
        const int v = (t >= d) ? part[t - d] : 0;
        __syncthreads();
        part[t] += v;
        __syncthreads();
    }
    int run = (t > 0) ? part[t - 1] : 0;
    for (int i = lo; i < hi; ++i) { off[i] = run; run += cnt[i]; }
    if (t == 0) off[N] = E;
}

__global__ __launch_bounds__(256) void scat_kernel(const int* __restrict__ rcv,
                                                   const int* __restrict__ off,
                                                   int* __restrict__ cur,
                                                   int* __restrict__ sid, int E) {
    const int t = blockIdx.x * 256 + threadIdx.x;
    if (t < E) {
        const int r = rcv[t];
        const int p = off[r] + atomicAdd(&cur[r], 1);
        sid[p] = t;
    }
}

// ---------------------------------------------------------------- edge kernel v2
// lane = edge. MLP as before; W_out pre-contracted per edge (linear, commutes
// with segment-sum): per-edge output is 128 floats [outS(32) | outV(32x3)].
// No atomics: coalesced float4 stores to msgbuf[e][0..127] via LDS re-staging.
__global__ __launch_bounds__(128, 2) void ek2(const float* __restrict__ edge_vec,
                                              const float* __restrict__ edge_len,
                                              const int*  __restrict__ senders,
                                              const float* __restrict__ w0,   // (8,64)
                                              const float* __restrict__ b0,   // 64
                                              const float* __restrict__ w1,   // (64,64)
                                              const float* __restrict__ b1,   // 64
                                              const float* __restrict__ b2,   // 128
                                              const float* __restrict__ w2t,  // (128,64)
                                              const float* __restrict__ Wo0,  // (64,32)
                                              const float* __restrict__ Wo1,  // (64,32)
                                              const float4* __restrict__ xall,
                                              float* __restrict__ msgbuf,     // E x 128
                                              int E) {
    __shared__ float sh[2][64][65];                 // 33.3 KiB/block, stride-65: conflict-free
    const int lane = threadIdx.x & 63;
    float (*st)[65] = sh[threadIdx.x >> 6];

    const int wave   = (blockIdx.x * blockDim.x + threadIdx.x) >> 6;
    const int nwaves = (gridDim.x * blockDim.x) >> 6;
    const int NP     = (E + 63) >> 6;

    for (int pass = wave; pass < NP; pass += nwaves) {
        const int base = pass * 64;
        int e = base + lane;
        const int ec = (e < E) ? e : (E - 1);

        const float ev0 = edge_vec[ec * 3 + 0];
        const float ev1 = edge_vec[ec * 3 + 1];
        const float ev2 = edge_vec[ec * 3 + 2];
        const float r   = edge_len[ec];
        const int  snd  = senders[ec];

        const float nrm = sqrtf(ev0 * ev0 + ev1 * ev1 + ev2 * ev2) + 1e-12f;
        const float sc  = SQ3F * __builtin_amdgcn_rcpf(nrm);
        const float Y0 = ev0 * sc, Y1 = ev1 * sc, Y2 = ev2 * sc;

        const float xcl  = fminf(fmaxf(r, 0.0f), 1.0f);
        const float gate = (r <= 1.0f) ? SQRT8F : 0.0f;
        float emb[8];
#pragma unroll
        for (int i = 0; i < 8; ++i) {
            const float d = xcl * 7.0f - (float)i;
            emb[i] = __expf(-0.5f * d * d) * gate;
        }

        // layer 1: 8 -> 64 in regs
        float h0[64];
#pragma unroll
        for (int o = 0; o < 64; ++o) {
            float a = b0[o];
#pragma unroll
            for (int i = 0; i < 8; ++i) a += emb[i] * w0[i * 64 + o];
            h0[o] = fast_silu(a);
        }

        // layer 2: 64 -> 64, h1 -> LDS column [i][lane]
#pragma unroll 1
        for (int ob = 0; ob < 64; ob += 8) {
            float a[8];
#pragma unroll
            for (int u = 0; u < 8; ++u) a[u] = b1[ob + u];
#pragma unroll
            for (int i = 0; i < 64; ++i) {
                const float hv = h0[i];
#pragma unroll
                for (int u = 0; u < 8; ++u) a[u] += hv * w1[i * 64 + ob + u];
            }
#pragma unroll
            for (int u = 0; u < 8; ++u) st[ob + u][lane] = fast_silu(a[u]);
        }

        // layer 3 + message + W_out contraction, accumulated over m
        const float4* xrow = xall + (size_t)snd * 32;
        float outS[32], tA[32], oV[96];
#pragma unroll
        for (int k = 0; k < 32; ++k) { outS[k] = 0.f; tA[k] = 0.f; }
#pragma unroll
        for (int k = 0; k < 96; ++k) oV[k] = 0.f;

#pragma unroll 1
        for (int m = 0; m < 32; ++m) {
            const float* r0 = w2t + m * 64;
            const float* r1 = w2t + (32 + m) * 64;
            const float* r2 = w2t + (64 + m) * 64;
            const float* r3 = w2t + (96 + m) * 64;
            float d0 = b2[m], d1 = b2[32 + m], d2 = b2[64 + m], d3 = b2[96 + m];
#pragma unroll
            for (int i = 0; i < 64; ++i) {
                const float hv = st[i][lane];
                d0 += hv * r0[i]; d1 += hv * r1[i];
                d2 += hv * r2[i]; d3 += hv * r3[i];
            }
            const float4 g = xrow[m];
            const float ss = g.x;
            const float dv = g.y * Y0 + g.z * Y1 + g.w * Y2;
            const float a0 = d0 * ss;
            const float a3 = d3 * dv * (1.0f / SQ3F);
            const float t1 = d1 * ss;
            const float p0 = d2 * g.y, p1 = d2 * g.z, p2 = d2 * g.w;
            const float* wa = Wo0 + m * 32;
            const float* wb = Wo0 + (32 + m) * 32;
            const float* wc = Wo1 + m * 32;
            const float* wd = Wo1 + (32 + m) * 32;
#pragma unroll
            for (int k = 0; k < 32; ++k) {
                outS[k] += a0 * wa[k] + a3 * wb[k];
                tA[k]   += t1 * wc[k];
                const float wv = wd[k];
                oV[k * 3 + 0] += p0 * wv;
                oV[k * 3 + 1] += p1 * wv;
                oV[k * 3 + 2] += p2 * wv;
            }
        }
        // fold the m1 (Y-outer) term
#pragma unroll
        for (int k = 0; k < 32; ++k) {
            oV[k * 3 + 0] += tA[k] * Y0;
            oV[k * 3 + 1] += tA[k] * Y1;
            oV[k * 3 + 2] += tA[k] * Y2;
        }

        // ---- coalesced writeback via LDS re-staging (h1 tile is dead now) ----
        // chunk 0: floats 0..63 = [outS(32) | oV(0..31)]
#pragma unroll
        for (int j = 0; j < 32; ++j) st[j][lane] = outS[j];
#pragma unroll
        for (int j = 32; j < 64; ++j) st[j][lane] = oV[j - 32];
        {
            const int es = lane >> 4;
            const int j4 = (lane & 15) * 4;
#pragma unroll
            for (int rr = 0; rr < 16; ++rr) {
                const int ee = rr * 4 + es;
                if (base + ee < E) {
                    float4 v;
                    v.x = st[j4 + 0][ee]; v.y = st[j4 + 1][ee];
                    v.z = st[j4 + 2][ee]; v.w = st[j4 + 3][ee];
                    *reinterpret_cast<float4*>(msgbuf + (size_t)(base + ee) * 128 + j4) = v;
                }
            }
        }
        // chunk 1: floats 64..127 = oV(32..95)
#pragma unroll
        for (int j = 0; j < 64; ++j) st[j][lane] = oV[32 + j];
        {
            const int es = lane >> 4;
            const int j4 = (lane & 15) * 4;
#pragma unroll
            for (int rr = 0; rr < 16; ++rr) {
                const int ee = rr * 4 + es;
                if (base + ee < E) {
                    float4 v;
                    v.x = st[j4 + 0][ee]; v.y = st[j4 + 1][ee];
                    v.z = st[j4 + 2][ee]; v.w = st[j4 + 3][ee];
                    *reinterpret_cast<float4*>(msgbuf + (size_t)(base + ee) * 128 + 64 + j4) = v;
                }
            }
        }
    }
}

// ---------------------------------------------------------------- gather kernel
// one wave per node: sum incoming pre-contracted messages, scale, write out.
__global__ __launch_bounds__(256) void gk(const float* __restrict__ msgbuf,
                                          const int* __restrict__ off,
                                          const int* __restrict__ sid,
                                          float* __restrict__ out, int N) {
    const int lane = threadIdx.x & 63;
    const int n = (blockIdx.x * 256 + threadIdx.x) >> 6;
    if (n >= N) return;
    const int lo = off[n], hi = off[n + 1];
    float a0 = 0.f, a1 = 0.f;
    for (int i = lo; i < hi; ++i) {
        const int eid = sid[i];
        const float2 v = *reinterpret_cast<const float2*>(msgbuf + (size_t)eid * 128 + lane * 2);
        a0 += v.x; a1 += v.y;
    }
    const float s = 1.0f / 128.0f;                  // (1/sqrt(64)) * (1/16)
    float2 o; o.x = a0 * s; o.y = a1 * s;
    *reinterpret_cast<float2*>(out + (size_t)n * 128 + lane * 2) = o;
}

// ---------------------------------------------------------------- fallback (round-3 path)
__global__ __launch_bounds__(128) void ek(const float* __restrict__ edge_vec,
                                          const float* __restrict__ edge_len,
                                          const int*  __restrict__ senders,
                                          const int*  __restrict__ receivers,
                                          const float* __restrict__ w0,
                                          const float* __restrict__ b0,
                                          const float* __restrict__ w1,
                                          const float* __restrict__ b1,
                                          const float* __restrict__ b2,
                                          const float* __restrict__ w2t,
                                          const float4* __restrict__ xall,
                                          float* __restrict__ msg, int E) {
    __shared__ float h1t[2][64][64];
    const int lane = threadIdx.x & 63;
    float (*h1w)[64] = h1t[threadIdx.x >> 6];
    const int wave   = (blockIdx.x * blockDim.x + threadIdx.x) >> 6;
    const int nwaves = (gridDim.x * blockDim.x) >> 6;
    const int NP     = (E + 63) >> 6;
    for (int pass = wave; pass < NP; pass += nwaves) {
        int e = pass * 64 + lane;
        const bool valid = e < E;
        if (!valid) e = E - 1;
        const float ev0 = edge_vec[e * 3 + 0];
        const float ev1 = edge_vec[e * 3 + 1];
        const float ev2 = edge_vec[e * 3 + 2];
        const float r   = edge_len[e];
        const int snd = senders[e];
        const int rcv = receivers[e];
        const float nrm = sqrtf(ev0 * ev0 + ev1 * ev1 + ev2 * ev2) + 1e-12f;
        const float sc  = SQ3F * __builtin_amdgcn_rcpf(nrm);
        const float Y0 = ev0 * sc, Y1 = ev1 * sc, Y2 = ev2 * sc;
        const float xcl  = fminf(fmaxf(r, 0.0f), 1.0f);
        const float gate = (r <= 1.0f) ? SQRT8F : 0.0f;
        float emb[8];
#pragma unroll
        for (int i = 0; i < 8; ++i) {
            const float d = xcl * 7.0f - (float)i;
            emb[i] = __expf(-0.5f * d * d) * gate;
        }
        float h0[64];
#pragma unroll
        for (int o = 0; o < 64; ++o) {
            float a = b0[o];
#pragma unroll
            for (int i = 0; i < 8; ++i) a += emb[i] * w0[i * 64 + o];
            h0[o] = fast_silu(a);
        }
#pragma unroll 1
        for (int ob = 0; ob < 64; ob += 8) {
            float a[8];
#pragma unroll
            for (int u = 0; u < 8; ++u) a[u] = b1[ob + u];
#pragma unroll
            for (int i = 0; i < 64; ++i) {
                const float hv = h0[i];
#pragma unroll
                for (int u = 0; u < 8; ++u) a[u] += hv * w1[i * 64 + ob + u];
            }
#pragma unroll
            for (int u = 0; u < 8; ++u) h1w[ob + u][lane] = fast_silu(a[u]);
        }
        const float4* xrow = xall + (size_t)snd * 32;
        float* mrow = msg + (size_t)rcv * 256;
#pragma unroll 1
        for (int m = 0; m < 32; ++m) {
            const float* r0 = w2t + m * 64;
            const float* r1 = w2t + (32 + m) * 64;
            const float* r2 = w2t + (64 + m) * 64;
            const float* r3 = w2t + (96 + m) * 64;
            float d0 = b2[m], d1 = b2[32 + m], d2 = b2[64 + m], d3 = b2[96 + m];
#pragma unroll
            for (int i = 0; i < 64; ++i) {
                const float hv = h1w[i][lane];
                d0 += hv * r0[i]; d1 += hv * r1[i];
                d2 += hv * r2[i]; d3 += hv * r3[i];
            }
            const float4 g = xrow[m];
            if (valid) {
                const float ss = g.x;
                const float t1 = d1 * ss;
                const float dv = g.y * Y0 + g.z * Y1 + g.w * Y2;
                atomicAdd(mrow + m,               d0 * ss);
                atomicAdd(mrow + 32 + m,          d3 * dv * (1.0f / SQ3F));
                atomicAdd(mrow + 64 + m * 3 + 0,  t1 * Y0);
                atomicAdd(mrow + 64 + m * 3 + 1,  t1 * Y1);
                atomicAdd(mrow + 64 + m * 3 + 2,  t1 * Y2);
                atomicAdd(mrow + 160 + m * 3 + 0, d2 * g.y);
                atomicAdd(mrow + 160 + m * 3 + 1, d2 * g.z);
                atomicAdd(mrow + 160 + m * 3 + 2, d2 * g.w);
            }
        }
    }
}

__global__ __launch_bounds__(256) void out_kernel(const float* __restrict__ msg,
                                                  const float* __restrict__ Wo0,
                                                  const float* __restrict__ Wo1,
                                                  float* __restrict__ out, int N) {
    __shared__ float s0[2048], s1[2048];
    for (int i = threadIdx.x; i < 2048; i += 256) { s0[i] = Wo0[i]; s1[i] = Wo1[i]; }
    __syncthreads();
    const int t = blockIdx.x * 256 + threadIdx.x;
    const int n = t >> 7, j = t & 127;
    if (n >= N) return;
    const float* mrow = msg + (size_t)n * 256;
    float acc = 0.0f;
    if (j < 32) {
#pragma unroll
        for (int mm = 0; mm < 64; ++mm) acc += mrow[mm] * s0[mm * 32 + j];
    } else {
        const int jj = j - 32;
        const int k = jj / 3, c = jj - 3 * k;
        const float* mv = mrow + 64 + c;
#pragma unroll
        for (int mm = 0; mm < 64; ++mm) acc += mv[mm * 3] * s1[mm * 32 + k];
    }
    out[(size_t)n * 128 + j] = acc * (1.0f / 128.0f);
}

extern "C" void kernel_launch(void* const* d_in, const int* in_sizes, int n_in,
                              void* d_out, int out_size, void* d_ws, size_t ws_size,
                              hipStream_t stream) {
    const float* node_feats = (const float*)d_in[0];
    const float* edge_vec   = (const float*)d_in[1];
    const float* edge_len   = (const float*)d_in[2];
    const int*   senders    = (const int*)d_in[3];
    const int*   receivers  = (const int*)d_in[4];
    const float* W_up0  = (const float*)d_in[6];
    const float* W_up1  = (const float*)d_in[7];
    const float* mlp_w0 = (const float*)d_in[8];
    const float* mlp_b0 = (const float*)d_in[9];
    const float* mlp_w1 = (const float*)d_in[10];
    const float* mlp_b1 = (const float*)d_in[11];
    const float* mlp_w2 = (const float*)d_in[12];
    const float* mlp_b2 = (const float*)d_in[13];
    const float* W_out0 = (const float*)d_in[14];
    const float* W_out1 = (const float*)d_in[15];

    const int N = in_sizes[0] / 128;
    const int E = in_sizes[1] / 3;

    float* xall = (float*)d_ws;                        // N*128 f32
    float* w2t  = xall + (size_t)N * 128;              // 8192 f32
    int*   cnt  = (int*)(w2t + 8192);                  // N
    int*   off  = cnt + N;                             // N+1
    int*   cur  = off + N + 1;                         // N
    int*   sid  = cur + N;                             // E
    uintptr_t mp = (uintptr_t)(sid + E);
    mp = (mp + 255) & ~(uintptr_t)255;
    float* msgbuf = (float*)mp;                        // E*128 f32 (410 MB)
    const size_t need = (mp - (uintptr_t)d_ws) + (size_t)E * 128 * sizeof(float);

    tr_kernel<<<32, 256, 0, stream>>>(mlp_w2, w2t);
    up_kernel<<<(N * 32 + 255) / 256, 256, 0, stream>>>(node_feats, W_up0, W_up1, xall, N);

    if (ws_size >= need) {
        // ---- sorted / materialized path (no hot atomics) ----
        hipMemsetAsync(cnt, 0, (size_t)(3 * N + 1) * sizeof(int), stream);
        hist_kernel<<<(E + 255) / 256, 256, 0, stream>>>(receivers, cnt, E);
        scan_kernel<<<1, 1024, 0, stream>>>(cnt, off, N, E);
        scat_kernel<<<(E + 255) / 256, 256, 0, stream>>>(receivers, off, cur, sid, E);
        ek2<<<(E + 127) / 128, 128, 0, stream>>>(edge_vec, edge_len, senders,
                                                 mlp_w0, mlp_b0, mlp_w1, mlp_b1, mlp_b2,
                                                 w2t, W_out0, W_out1,
                                                 (const float4*)xall, msgbuf, E);
        gk<<<(N * 64 + 255) / 256, 256, 0, stream>>>(msgbuf, off, sid, (float*)d_out, N);
    } else {
        // ---- fallback: round-3 atomic path ----
        float* msg = (float*)(w2t + 8192);             // N*256 f32
        hipMemsetAsync(msg, 0, (size_t)N * 256 * sizeof(float), stream);
        ek<<<1280, 128, 0, stream>>>(edge_vec, edge_len, senders, receivers,
                                     mlp_w0, mlp_b0, mlp_w1, mlp_b1, mlp_b2, w2t,
                                     (const float4*)xall, msg, E);
        out_kernel<<<(N * 128 + 255) / 256, 256, 0, stream>>>(msg, W_out0, W_out1,
                                                              (float*)d_out, N);
    }
}

// Round 9
// 2494.524 us; speedup vs baseline: 4.2196x; 4.2099x over previous
//
#include <hip/hip_runtime.h>
#include <math.h>

#define SQ3F   1.7320508075688772f
#define SQRT8F 2.8284271247461903f
#define OSCALE (1.0f / 128.0f)   // (1/sqrt(64)) * (1/AVG=16)

__device__ __forceinline__ float fast_silu(float x) {
    return x * __builtin_amdgcn_rcpf(1.0f + __expf(-x));
}

// ---------------------------------------------------------------- transpose w2
__global__ __launch_bounds__(256) void tr_kernel(const float* __restrict__ w2,
                                                 float* __restrict__ w2t) {
    const int t = blockIdx.x * 256 + threadIdx.x;   // 8192 = 128 x 64
    if (t < 8192) {
        const int o = t >> 6, i = t & 63;
        w2t[t] = w2[i * 128 + o];                   // w2t[o][i] = w2[i][o]
    }
}

// ---------------------------------------------------------------- up-projection
// xall[n][m] = float4{ xs[n][m], xv[n][m][0], xv[n][m][1], xv[n][m][2] }
__global__ __launch_bounds__(256) void up_kernel(const float* __restrict__ nf,
                                                 const float* __restrict__ Wu0,
                                                 const float* __restrict__ Wu1,
                                                 float* __restrict__ xall, int N) {
    __shared__ float sW0[1024], sW1[1024];
    for (int i = threadIdx.x; i < 1024; i += 256) { sW0[i] = Wu0[i]; sW1[i] = Wu1[i]; }
    __syncthreads();
    const int t = blockIdx.x * 256 + threadIdx.x;
    const int n = t >> 5, k = t & 31;
    if (n >= N) return;
    const float* row = nf + (size_t)n * 128;
    float a0 = 0.f, a1 = 0.f, a2 = 0.f, a3 = 0.f;
#pragma unroll
    for (int m = 0; m < 32; ++m) {
        const float wa = sW0[m * 32 + k], wb = sW1[m * 32 + k];
        a0 += row[m] * wa;
        a1 += row[32 + m * 3 + 0] * wb;
        a2 += row[32 + m * 3 + 1] * wb;
        a3 += row[32 + m * 3 + 2] * wb;
    }
    const float s = 0.17677669529663687f;  // 1/sqrt(32)
    float4 o; o.x = a0 * s; o.y = a1 * s; o.z = a2 * s; o.w = a3 * s;
    reinterpret_cast<float4*>(xall)[(size_t)n * 32 + k] = o;
}

// ---------------------------------------------------------------- CSR build
__global__ __launch_bounds__(256) void hist_kernel(const int* __restrict__ rcv,
                                                   int* __restrict__ cnt, int E) {
    const int t = blockIdx.x * 256 + threadIdx.x;
    if (t < E) atomicAdd(&cnt[rcv[t]], 1);
}

__global__ __launch_bounds__(1024) void scan_kernel(const int* __restrict__ cnt,
                                                    int* __restrict__ off, int N, int E) {
    __shared__ int part[1024];
    const int t = threadIdx.x;
    const int CH = (N + 1023) / 1024;
    const int lo = t * CH;
    const int hi = (lo + CH < N) ? lo + CH : N;
    int s = 0;
    for (int i = lo; i < hi; ++i) s += cnt[i];
    part[t] = s;
    __syncthreads();
    for (int d = 1; d < 1024; d <<= 1) {
        const int v = (t >= d) ? part[t - d] : 0;
        __syncthreads();
        part[t] += v;
        __syncthreads();
    }
    int run = (t > 0) ? part[t - 1] : 0;
    for (int i = lo; i < hi; ++i) { off[i] = run; run += cnt[i]; }
    if (t == 0) off[N] = E;
}

__global__ __launch_bounds__(256) void scat_kernel(const int* __restrict__ rcv,
                                                   const int* __restrict__ off,
                                                   int* __restrict__ cur,
                                                   int* __restrict__ sid, int E) {
    const int t = blockIdx.x * 256 + threadIdx.x;
    if (t < E) {
        const int r = rcv[t];
        const int p = off[r] + atomicAdd(&cur[r], 1);
        sid[p] = t;
    }
}

// ---------------------------------------------------------------- wave->node assignment
// node n is owned by wave w = off[n] >> 6 (monotone in n => contiguous ranges,
// each node owned by exactly one wave). Waves then need ZERO output atomics.
__global__ __launch_bounds__(256) void wassign_kernel(const int* __restrict__ off,
                                                      int* __restrict__ wlo,
                                                      int* __restrict__ whi,
                                                      int N, int NW) {
    const int n = blockIdx.x * 256 + threadIdx.x;
    if (n < N) {
        int w = off[n] >> 6;
        if (w >= NW) w = NW - 1;
        atomicMin(&wlo[w], n);
        atomicMax(&whi[w], n);
    }
}

// ---------------------------------------------------------------- edge kernel v4
// One wave per block. Wave w owns nodes [wlo[w], whi[w]] and processes their
// edges [off[nlo], off[nhi+1]) in batches of 64 (lane = edge). Per-edge MLP
// with wave-uniform (SGPR) weights + W_out pre-contraction; per-node sums
// carried in registers across batches; completed nodes emitted with PLAIN
// coalesced stores (no atomics anywhere on the output path).
__global__ __launch_bounds__(64, 2) void ek4(const float* __restrict__ edge_vec,
                                             const float* __restrict__ edge_len,
                                             const int*  __restrict__ senders,
                                             const int*  __restrict__ receivers,
                                             const int*  __restrict__ sid,
                                             const int*  __restrict__ off,
                                             const int*  __restrict__ wlo,
                                             const int*  __restrict__ whi,
                                             const float* __restrict__ w0,   // (8,64)
                                             const float* __restrict__ b0,   // 64
                                             const float* __restrict__ w1,   // (64,64)
                                             const float* __restrict__ b1,   // 64
                                             const float* __restrict__ b2,   // 128
                                             const float* __restrict__ w2t,  // (128,64)
                                             const float* __restrict__ Wo0,  // (64,32)
                                             const float* __restrict__ Wo1,  // (64,32)
                                             const float4* __restrict__ xall,
                                             float* __restrict__ outp,       // N x 128 (zeroed)
                                             int E) {
    __shared__ float st[64][65];                    // 16.6 KiB, conflict-free both ways
    __shared__ int   rcvt[64];
    const int lane = threadIdx.x;
    const int w = blockIdx.x;
    const int nlo = wlo[w], nhi = whi[w];
    if (nhi < nlo) return;                          // no nodes assigned
    const int estart = off[nlo], eend = off[nhi + 1];
    if (estart >= eend) return;                     // only zero-degree nodes

    int   rprev = -1;
    float accA = 0.f, accB = 0.f;

    for (int bs = estart; bs < eend; bs += 64) {
        const int nv = (eend - bs < 64) ? (eend - bs) : 64;   // wave-uniform
        const int sp = (lane < nv) ? (bs + lane) : (eend - 1);
        const int e  = sid[sp];
        rcvt[lane] = receivers[e];

        const float ev0 = edge_vec[e * 3 + 0];
        const float ev1 = edge_vec[e * 3 + 1];
        const float ev2 = edge_vec[e * 3 + 2];
        const float r   = edge_len[e];
        const int  snd  = senders[e];

        const float nrm = sqrtf(ev0 * ev0 + ev1 * ev1 + ev2 * ev2) + 1e-12f;
        const float sc  = SQ3F * __builtin_amdgcn_rcpf(nrm);
        const float Y0 = ev0 * sc, Y1 = ev1 * sc, Y2 = ev2 * sc;

        const float xcl  = fminf(fmaxf(r, 0.0f), 1.0f);
        const float gate = (r <= 1.0f) ? SQRT8F : 0.0f;
        float emb[8];
#pragma unroll
        for (int i = 0; i < 8; ++i) {
            const float d = xcl * 7.0f - (float)i;
            emb[i] = __expf(-0.5f * d * d) * gate;
        }

        // layer 1: 8 -> 64 in regs (weights wave-uniform -> SGPR)
        float h0[64];
#pragma unroll
        for (int o = 0; o < 64; ++o) {
            float a = b0[o];
#pragma unroll
            for (int i = 0; i < 8; ++i) a += emb[i] * w0[i * 64 + o];
            h0[o] = fast_silu(a);
        }

        // layer 2: 64 -> 64, h1 -> LDS column [i][lane] (own column only)
#pragma unroll 1
        for (int ob = 0; ob < 64; ob += 8) {
            float a[8];
#pragma unroll
            for (int u = 0; u < 8; ++u) a[u] = b1[ob + u];
#pragma unroll
            for (int i = 0; i < 64; ++i) {
                const float hv = h0[i];
#pragma unroll
                for (int u = 0; u < 8; ++u) a[u] += hv * w1[i * 64 + ob + u];
            }
#pragma unroll
            for (int u = 0; u < 8; ++u) st[ob + u][lane] = fast_silu(a[u]);
        }

        // layer 3 + message + W_out contraction (accumulated over m)
        const float4* xrow = xall + (size_t)snd * 32;
        float outS[32], tA[32], oV[96];
#pragma unroll
        for (int k = 0; k < 32; ++k) { outS[k] = 0.f; tA[k] = 0.f; }
#pragma unroll
        for (int k = 0; k < 96; ++k) oV[k] = 0.f;

#pragma unroll 1
        for (int m = 0; m < 32; ++m) {
            const float* r0 = w2t + m * 64;
            const float* r1 = w2t + (32 + m) * 64;
            const float* r2 = w2t + (64 + m) * 64;
            const float* r3 = w2t + (96 + m) * 64;
            float d0 = b2[m], d1 = b2[32 + m], d2 = b2[64 + m], d3 = b2[96 + m];
#pragma unroll
            for (int i = 0; i < 64; ++i) {
                const float hv = st[i][lane];
                d0 += hv * r0[i]; d1 += hv * r1[i];
                d2 += hv * r2[i]; d3 += hv * r3[i];
            }
            const float4 g = xrow[m];
            const float ss = g.x;
            const float dv = g.y * Y0 + g.z * Y1 + g.w * Y2;
            const float a0 = d0 * ss;                   // m0[m]
            const float a3 = d3 * dv * (1.0f / SQ3F);   // m3[m]
            const float t1 = d1 * ss;                   // m1[m] coefficient of Y
            const float p0 = d2 * g.y, p1 = d2 * g.z, p2 = d2 * g.w;  // m2[m][c]
            const float* wa = Wo0 + m * 32;
            const float* wb = Wo0 + (32 + m) * 32;
            const float* wc = Wo1 + m * 32;
            const float* wd = Wo1 + (32 + m) * 32;
#pragma unroll
            for (int k = 0; k < 32; ++k) {
                outS[k] += a0 * wa[k] + a3 * wb[k];
                tA[k]   += t1 * wc[k];
                const float wv = wd[k];
                oV[k * 3 + 0] += p0 * wv;
                oV[k * 3 + 1] += p1 * wv;
                oV[k * 3 + 2] += p2 * wv;
            }
        }
        // fold the m1 (Y-outer) term
#pragma unroll
        for (int k = 0; k < 32; ++k) {
            oV[k * 3 + 0] += tA[k] * Y0;
            oV[k * 3 + 1] += tA[k] * Y1;
            oV[k * 3 + 2] += tA[k] * Y2;
        }

        // ---- chunk 0: channels 0..63 = [outS(32) | oV(0..31)] ----
#pragma unroll
        for (int j = 0; j < 32; ++j) st[j][lane]      = outS[j];
#pragma unroll
        for (int j = 0; j < 32; ++j) st[32 + j][lane] = oV[j];
        __syncthreads();
        if (rprev < 0) rprev = rcvt[0];
        {
            int rA = rprev; float a = accA;
            for (int ee = 0; ee < nv; ++ee) {
                const int rc = rcvt[ee];                // wave-uniform
                if (rc != rA) {                         // run closed: plain store
                    outp[(size_t)rA * 128 + lane] = a * OSCALE;
                    a = 0.f; rA = rc;
                }
                a += st[lane][ee];                      // row=channel, col=edge
            }
            accA = a;
        }
        __syncthreads();

        // ---- chunk 1: channels 64..127 = oV(32..95) ----
#pragma unroll
        for (int j = 0; j < 64; ++j) st[j][lane] = oV[32 + j];
        __syncthreads();
        {
            int rB = rprev; float b = accB;
            for (int ee = 0; ee < nv; ++ee) {
                const int rc = rcvt[ee];
                if (rc != rB) {
                    outp[(size_t)rB * 128 + 64 + lane] = b * OSCALE;
                    b = 0.f; rB = rc;
                }
                b += st[lane][ee];
            }
            accB = b; rprev = rB;                       // rB == rA by construction
        }
        __syncthreads();                                // protect st/rcvt for next batch
    }

    // final (still-open) run
    outp[(size_t)rprev * 128 + lane]      = accA * OSCALE;
    outp[(size_t)rprev * 128 + 64 + lane] = accB * OSCALE;
}

extern "C" void kernel_launch(void* const* d_in, const int* in_sizes, int n_in,
                              void* d_out, int out_size, void* d_ws, size_t ws_size,
                              hipStream_t stream) {
    const float* node_feats = (const float*)d_in[0];
    const float* edge_vec   = (const float*)d_in[1];
    const float* edge_len   = (const float*)d_in[2];
    const int*   senders    = (const int*)d_in[3];
    const int*   receivers  = (const int*)d_in[4];
    const float* W_up0  = (const float*)d_in[6];
    const float* W_up1  = (const float*)d_in[7];
    const float* mlp_w0 = (const float*)d_in[8];
    const float* mlp_b0 = (const float*)d_in[9];
    const float* mlp_w1 = (const float*)d_in[10];
    const float* mlp_b1 = (const float*)d_in[11];
    const float* mlp_w2 = (const float*)d_in[12];
    const float* mlp_b2 = (const float*)d_in[13];
    const float* W_out0 = (const float*)d_in[14];
    const float* W_out1 = (const float*)d_in[15];

    const int N  = in_sizes[0] / 128;
    const int E  = in_sizes[1] / 3;
    const int NW = (E + 63) / 64;

    // workspace layout (~30 MB; round-3 path proved ws >= ~77 MB)
    float* xall = (float*)d_ws;                        // N*128 f32 (25.6 MB)
    float* w2t  = xall + (size_t)N * 128;              // 8192 f32
    int*   cnt  = (int*)(w2t + 8192);                  // N
    int*   off  = cnt + N;                             // N+1
    int*   cur  = off + N + 1;                         // N
    int*   sid  = cur + N;                             // E
    int*   wlo  = sid + E;                             // NW
    int*   whi  = wlo + NW;                            // NW

    tr_kernel<<<32, 256, 0, stream>>>(mlp_w2, w2t);
    up_kernel<<<(N * 32 + 255) / 256, 256, 0, stream>>>(node_feats, W_up0, W_up1, xall, N);

    // CSR sort by receiver
    hipMemsetAsync(cnt, 0, (size_t)(3 * N + 1) * sizeof(int), stream);
    hist_kernel<<<(E + 255) / 256, 256, 0, stream>>>(receivers, cnt, E);
    scan_kernel<<<1, 1024, 0, stream>>>(cnt, off, N, E);
    scat_kernel<<<(E + 255) / 256, 256, 0, stream>>>(receivers, off, cur, sid, E);

    // wave -> node ownership (0x7f7f7f7f = +big sentinel, 0xff = -1)
    hipMemsetAsync(wlo, 0x7f, (size_t)NW * sizeof(int), stream);
    hipMemsetAsync(whi, 0xff, (size_t)NW * sizeof(int), stream);
    wassign_kernel<<<(N + 255) / 256, 256, 0, stream>>>(off, wlo, whi, N, NW);

    // zero-degree nodes stay 0; owned nodes are plain-stored by ek4
    hipMemsetAsync(d_out, 0, (size_t)out_size * sizeof(float), stream);
    ek4<<<NW, 64, 0, stream>>>(edge_vec, edge_len, senders, receivers, sid, off,
                               wlo, whi,
                               mlp_w0, mlp_b0, mlp_w1, mlp_b1, mlp_b2,
                               w2t, W_out0, W_out1,
                               (const float4*)xall, (float*)d_out, E);
}